// Round 1
// baseline (806.502 us; speedup 1.0000x reference)
//
#include <hip/hip_runtime.h>

typedef __attribute__((ext_vector_type(8))) short bfrag_t;   // 8 x bf16 (4 VGPRs)
typedef __attribute__((ext_vector_type(4))) float f4_t;

#define LOG_2PI   1.8378770664093453f
#define TWO_LOG2  1.3862943611198906f
#define T_TILES   8            // 16-point tiles per wave
#define BLOCK     256          // 4 waves
#define PTS_BLK   512          // 4 waves * 8 tiles * 16 pts

struct SM {
  uint4    afr[2][2][8][64];   // 32KB [buf][mlp][frag=q*4+n][lane] pre-swizzled bf16 W2 A-frags
  float2   c1b1[6][2][64];     // 6KB  (w1[j][jm], b1[j]) fp32
  unsigned wb[6][2][64];       // 3KB  hi=bf16(w3[jo][h]) lo=bf16(b2[h])
  float4   pts[PTS_BLK];       // 8KB  (e0, e1, base, tw)
  float    wsum[4];
};

__device__ __forceinline__ unsigned pkbf(float lo, float hi) {
  unsigned r;
  asm("v_cvt_pk_bf16_f32 %0, %1, %2" : "=v"(r) : "v"(lo), "v"(hi));
  return r;
}

// Stage one layer's W2 (both MLPs) into LDS as MFMA A-fragments (bf16).
// A-frag layout for mfma_f32_16x16x32_bf16: lane l holds A[16n + (l&15)][32q + 8*(l>>4) + e], e=0..7
__device__ __forceinline__ void stage_layer(SM* sm, const float* sW2, const float* tW2,
                                            int layer, int buf, int tid) {
  #pragma unroll
  for (int it = 0; it < 4; ++it) {
    int idx = tid + it * BLOCK;          // 0..1023
    int l = idx & 63, f = (idx >> 6) & 7, m = (idx >> 9) & 1;
    int n = f & 3, q = f >> 2;
    int row = 16 * n + (l & 15), kb = 32 * q + 8 * (l >> 4);
    const float* src = (m ? tW2 : sW2) + layer * 4096 + row * 64 + kb;
    float4 a = *(const float4*)src;
    float4 b = *(const float4*)(src + 4);
    uint4 v = make_uint4(pkbf(a.x, a.y), pkbf(a.z, a.w), pkbf(b.x, b.y), pkbf(b.z, b.w));
    sm->afr[buf][m][f][l] = v;
  }
}

__global__ __launch_bounds__(BLOCK, 2) void ihll_kernel(
    const float* __restrict__ pred, const float* __restrict__ targ, const float* __restrict__ twp,
    const float* __restrict__ sW1, const float* __restrict__ sB1, const float* __restrict__ sW2,
    const float* __restrict__ sB2, const float* __restrict__ sW3, const float* __restrict__ sB3,
    const float* __restrict__ tW1, const float* __restrict__ tB1, const float* __restrict__ tW2,
    const float* __restrict__ tB2, const float* __restrict__ tW3, const float* __restrict__ tB3,
    float* __restrict__ out, int M) {
  __shared__ SM sm;
  const int tid  = threadIdx.x;
  const int lane = tid & 63, wave = tid >> 6;
  const int pr   = lane & 15, g = lane >> 4;
  const int pbase = blockIdx.x * PTS_BLK;

  // ---- stage per-layer small tables (all 6 layers, once) ----
  for (int idx = tid; idx < 768; idx += BLOCK) {
    int i = idx >> 7, r = idx & 127, m = r >> 6, j = r & 63;
    int jo = i & 1, jm = jo ^ 1;                    // MASK[i]: i even -> m=[0,1] (jm=1, jo=0)
    const float* w1 = m ? tW1 : sW1;  const float* b1 = m ? tB1 : sB1;
    const float* w3 = m ? tW3 : sW3;  const float* b2 = m ? tB2 : sB2;
    sm.c1b1[i][m][j] = make_float2(w1[i * 128 + j * 2 + jm], b1[i * 64 + j]);
    sm.wb[i][m][j]   = pkbf(b2[i * 64 + j], w3[i * 128 + jo * 64 + j]);  // lo=b2, hi=w3
  }
  // ---- stage point data: error, base term, weight ----
  #pragma unroll
  for (int it = 0; it < 2; ++it) {
    int idx = tid + it * BLOCK;
    int P = pbase + idx;
    float4 o = make_float4(0.f, 0.f, 0.f, 0.f);
    if (P < M) {
      float4 p4 = ((const float4*)pred)[P];
      float2 t2 = ((const float2*)targ)[P];
      float w   = twp[P];
      float s0 = sqrtf(fabsf(p4.z)), s1 = sqrtf(fabsf(p4.w));
      float e0 = (p4.x - t2.x) / (s0 + 1e-9f);
      float e1 = (p4.y - t2.y) / (s1 + 1e-9f);
      // sum_c [2*log(sigma_c) + log2 + |e_c|]
      float bs = 2.f * (logf(s0) + logf(s1)) + TWO_LOG2 + fabsf(e0) + fabsf(e1);
      o = make_float4(e0, e1, bs, w);
    }
    sm.pts[idx] = o;
  }
  stage_layer(&sm, sW2, tW2, 5, 0, tid);   // first layer processed is i=5
  __syncthreads();

  // ---- init per-lane flow state: lane owns point (wave,tile,pr), replicated over g ----
  const int wbase = wave * (T_TILES * 16);
  float z0[T_TILES], z1[T_TILES], ldet[T_TILES];
  #pragma unroll
  for (int t = 0; t < T_TILES; ++t) {
    float4 v = sm.pts[wbase + t * 16 + pr];
    z0[t] = v.x; z1[t] = v.y; ldet[t] = 0.f;
  }

  // ---- layer loop: i = 5..0 ----
  #pragma unroll 1
  for (int li = 0; li < 6; ++li) {
    const int i = 5 - li;
    const int cur = li & 1;
    const int jo = i & 1;             // component written this layer
    const bool upd0 = (jo == 0);      // jo==0: input comp is z1, output z0

    // per-layer constants into registers
    uint4 af[2][8];
    #pragma unroll
    for (int m = 0; m < 2; ++m)
      #pragma unroll
      for (int f = 0; f < 8; ++f)
        af[m][f] = sm.afr[cur][m][f][lane];

    float c1v[2][16], b1r[2][16];
    #pragma unroll
    for (int m = 0; m < 2; ++m)
      #pragma unroll
      for (int q = 0; q < 2; ++q)
        #pragma unroll
        for (int e2 = 0; e2 < 4; ++e2) {
          float4 v = *(const float4*)&sm.c1b1[i][m][q * 32 + 8 * g + e2 * 2];
          c1v[m][q * 8 + e2 * 2]     = v.x; b1r[m][q * 8 + e2 * 2]     = v.y;
          c1v[m][q * 8 + e2 * 2 + 1] = v.z; b1r[m][q * 8 + e2 * 2 + 1] = v.w;
        }
    unsigned wbv[2][16];
    #pragma unroll
    for (int m = 0; m < 2; ++m)
      #pragma unroll
      for (int n = 0; n < 4; ++n) {
        uint4 v = *(const uint4*)&sm.wb[i][m][n * 16 + 4 * g];
        wbv[m][n * 4 + 0] = v.x; wbv[m][n * 4 + 1] = v.y;
        wbv[m][n * 4 + 2] = v.z; wbv[m][n * 4 + 3] = v.w;
      }
    const float b3s = sB3[i * 2 + jo];
    const float b3t = tB3[i * 2 + jo];

    if (li < 5) stage_layer(&sm, sW2, tW2, i - 1, cur ^ 1, tid);  // prefetch next layer

    #pragma unroll
    for (int t = 0; t < T_TILES; ++t) {
      const float zin = upd0 ? z1[t] : z0[t];   // masked-in component z[jm]
      float pre[2];
      #pragma unroll
      for (int m = 0; m < 2; ++m) {
        f4_t acc[4];
        #pragma unroll
        for (int n = 0; n < 4; ++n)
          #pragma unroll
          for (int r = 0; r < 4; ++r)
            acc[n][r] = __uint_as_float(wbv[m][n * 4 + r] << 16);   // init with b2
        #pragma unroll
        for (int q = 0; q < 2; ++q) {
          // layer 1: h1 = leaky(w1[:,jm]*zin + b1), this lane's 8 k-slots, as bf16 B-frag
          unsigned bb[4];
          #pragma unroll
          for (int e2 = 0; e2 < 4; ++e2) {
            float h0 = fmaf(c1v[m][q * 8 + e2 * 2],     zin, b1r[m][q * 8 + e2 * 2]);
            float h1 = fmaf(c1v[m][q * 8 + e2 * 2 + 1], zin, b1r[m][q * 8 + e2 * 2 + 1]);
            h0 = fmaxf(h0, 0.01f * h0);
            h1 = fmaxf(h1, 0.01f * h1);
            bb[e2] = pkbf(h0, h1);
          }
          bfrag_t B = __builtin_bit_cast(bfrag_t, make_uint4(bb[0], bb[1], bb[2], bb[3]));
          #pragma unroll
          for (int n = 0; n < 4; ++n)
            acc[n] = __builtin_amdgcn_mfma_f32_16x16x32_bf16(
                __builtin_bit_cast(bfrag_t, af[m][q * 4 + n]), B, acc[n], 0, 0, 0);
        }
        // layer 3: leaky(h2), dot with w3[jo], reduce over the 4 lane-groups
        float part = 0.f;
        #pragma unroll
        for (int n = 0; n < 4; ++n)
          #pragma unroll
          for (int r = 0; r < 4; ++r) {
            float h2 = acc[n][r];
            h2 = fmaxf(h2, 0.01f * h2);
            part = fmaf(__uint_as_float(wbv[m][n * 4 + r] & 0xffff0000u), h2, part);
          }
        part += __shfl_xor(part, 16);
        part += __shfl_xor(part, 32);
        pre[m] = part;
      }
      // coupling update
      float esv = __expf(2.f * (pre[0] + b3s));
      float sv  = 1.f - 2.f / (esv + 1.f);          // tanh
      float tv  = pre[1] + b3t;
      float zo  = upd0 ? z0[t] : z1[t];
      float zn  = (zo - tv) * __expf(-sv);
      if (upd0) z0[t] = zn; else z1[t] = zn;
      ldet[t] -= sv;
    }
    __syncthreads();
  }

  // ---- epilogue: prior + logdet -> loss contribution; reduce ----
  float csum = 0.f;
  #pragma unroll
  for (int t = 0; t < T_TILES; ++t) {
    float4 v = sm.pts[wbase + t * 16 + pr];
    float prior = -0.5f * (z0[t] * z0[t] + z1[t] * z1[t]) - LOG_2PI;
    float lphi  = prior + ldet[t];
    csum += (v.z - 2.f * lphi) * v.w;
  }
  #pragma unroll
  for (int off = 1; off <= 32; off <<= 1)
    csum += __shfl_xor(csum, off);
  if (lane == 0) sm.wsum[wave] = csum;
  __syncthreads();
  if (tid == 0) {
    float tot = sm.wsum[0] + sm.wsum[1] + sm.wsum[2] + sm.wsum[3];
    // /4 for the 4x group replication, /8192 = /pred.shape[0]
    atomicAdd(out, tot * (1.0f / 32768.0f));
  }
}

extern "C" void kernel_launch(void* const* d_in, const int* in_sizes, int n_in,
                              void* d_out, int out_size, void* d_ws, size_t ws_size,
                              hipStream_t stream) {
  const float* pred = (const float*)d_in[0];
  const float* targ = (const float*)d_in[1];
  const float* twp  = (const float*)d_in[2];
  const float* sW1 = (const float*)d_in[3];  const float* sB1 = (const float*)d_in[4];
  const float* sW2 = (const float*)d_in[5];  const float* sB2 = (const float*)d_in[6];
  const float* sW3 = (const float*)d_in[7];  const float* sB3 = (const float*)d_in[8];
  const float* tW1 = (const float*)d_in[9];  const float* tB1 = (const float*)d_in[10];
  const float* tW2 = (const float*)d_in[11]; const float* tB2 = (const float*)d_in[12];
  const float* tW3 = (const float*)d_in[13]; const float* tB3 = (const float*)d_in[14];

  const int M = in_sizes[2];               // N*K points
  const int blocks = (M + PTS_BLK - 1) / PTS_BLK;

  hipMemsetAsync(d_out, 0, sizeof(float), stream);
  hipLaunchKernelGGL(ihll_kernel, dim3(blocks), dim3(BLOCK), 0, stream,
                     pred, targ, twp, sW1, sB1, sW2, sB2, sW3, sB3,
                     tW1, tB1, tW2, tB2, tW3, tB3, (float*)d_out, M);
}

// Round 2
// 353.611 us; speedup vs baseline: 2.2808x; 2.2808x over previous
//
#include <hip/hip_runtime.h>

typedef __attribute__((ext_vector_type(8))) short bfrag_t;   // 8 x bf16 (4 VGPRs)
typedef __attribute__((ext_vector_type(4))) float f4_t;

#define LOG_2PI   1.8378770664093453f
#define TWO_LOG2  1.3862943611198906f
#define T_TILES   8            // 16-point tiles per wave
#define BLOCK     256          // 4 waves
#define PTS_BLK   512          // 4 waves * 8 tiles * 16 pts

struct SM {
  uint4    afr[2][2][8][64];   // 32KB [buf][mlp][frag=q*4+n][lane] pre-swizzled bf16 W2 A-frags
  float4   zst[PTS_BLK];       // 8KB  per-point flow state (z0, z1, ldet, pad)
  float2   c1b1[6][2][64];     // 6KB  (w1[j][jm], b1[j]) fp32
  float2   btw[PTS_BLK];       // 4KB  (base_term, weight)
  unsigned wb[6][2][64];       // 3KB  hi=bf16(w3[jo][h]) lo=bf16(b2[h])
  float    wsum[4];
};

__device__ __forceinline__ unsigned pkbf(float lo, float hi) {
  unsigned r;
  asm("v_cvt_pk_bf16_f32 %0, %1, %2" : "=v"(r) : "v"(lo), "v"(hi));
  return r;
}

// Stage one layer's W2 (both MLPs) into LDS as MFMA A-fragments (bf16).
// A-frag layout for mfma_f32_16x16x32_bf16: lane l holds A[16n + (l&15)][32q + 8*(l>>4) + e], e=0..7
__device__ __forceinline__ void stage_layer(SM* sm, const float* sW2, const float* tW2,
                                            int layer, int buf, int tid) {
  #pragma unroll
  for (int it = 0; it < 4; ++it) {
    int idx = tid + it * BLOCK;          // 0..1023
    int l = idx & 63, f = (idx >> 6) & 7, m = (idx >> 9) & 1;
    int n = f & 3, q = f >> 2;
    int row = 16 * n + (l & 15), kb = 32 * q + 8 * (l >> 4);
    const float* src = (m ? tW2 : sW2) + layer * 4096 + row * 64 + kb;
    float4 a = *(const float4*)src;
    float4 b = *(const float4*)(src + 4);
    uint4 v = make_uint4(pkbf(a.x, a.y), pkbf(a.z, a.w), pkbf(b.x, b.y), pkbf(b.z, b.w));
    sm->afr[buf][m][f][l] = v;
  }
}

__global__ __launch_bounds__(BLOCK, 1) void ihll_kernel(
    const float* __restrict__ pred, const float* __restrict__ targ, const float* __restrict__ twp,
    const float* __restrict__ sW1, const float* __restrict__ sB1, const float* __restrict__ sW2,
    const float* __restrict__ sB2, const float* __restrict__ sW3, const float* __restrict__ sB3,
    const float* __restrict__ tW1, const float* __restrict__ tB1, const float* __restrict__ tW2,
    const float* __restrict__ tB2, const float* __restrict__ tW3, const float* __restrict__ tB3,
    float* __restrict__ out, int M) {
  __shared__ SM sm;
  const int tid  = threadIdx.x;
  const int lane = tid & 63, wave = tid >> 6;
  const int pr   = lane & 15, g = lane >> 4;
  const int pbase = blockIdx.x * PTS_BLK;

  // ---- stage per-layer small tables (all 6 layers, once) ----
  for (int idx = tid; idx < 768; idx += BLOCK) {
    int i = idx >> 7, r = idx & 127, m = r >> 6, j = r & 63;
    int jo = i & 1, jm = jo ^ 1;                    // MASK[i]: i even -> m=[0,1] (jm=1, jo=0)
    const float* w1 = m ? tW1 : sW1;  const float* b1 = m ? tB1 : sB1;
    const float* w3 = m ? tW3 : sW3;  const float* b2 = m ? tB2 : sB2;
    sm.c1b1[i][m][j] = make_float2(w1[i * 128 + j * 2 + jm], b1[i * 64 + j]);
    sm.wb[i][m][j]   = pkbf(b2[i * 64 + j], w3[i * 128 + jo * 64 + j]);  // lo=b2, hi=w3
  }
  // ---- stage point data: flow state (z=error), base term, weight ----
  #pragma unroll
  for (int it = 0; it < 2; ++it) {
    int idx = tid + it * BLOCK;
    int P = pbase + idx;
    float4 zs = make_float4(0.f, 0.f, 0.f, 0.f);
    float2 bw = make_float2(0.f, 0.f);
    if (P < M) {
      float4 p4 = ((const float4*)pred)[P];
      float2 t2 = ((const float2*)targ)[P];
      float w   = twp[P];
      float s0 = sqrtf(fabsf(p4.z)), s1 = sqrtf(fabsf(p4.w));
      float e0 = (p4.x - t2.x) / (s0 + 1e-9f);
      float e1 = (p4.y - t2.y) / (s1 + 1e-9f);
      // sum_c [2*log(sigma_c) + log2 + |e_c|]
      float bs = 2.f * (logf(s0) + logf(s1)) + TWO_LOG2 + fabsf(e0) + fabsf(e1);
      zs = make_float4(e0, e1, 0.f, 0.f);
      bw = make_float2(bs, w);
    }
    sm.zst[idx] = zs;
    sm.btw[idx] = bw;
  }
  stage_layer(&sm, sW2, tW2, 5, 0, tid);   // first layer processed is i=5
  __syncthreads();

  const int wbase = wave * (T_TILES * 16);

  // ---- layer loop: i = 5..0 ----
  #pragma unroll 1
  for (int li = 0; li < 6; ++li) {
    const int i = 5 - li;
    const int cur = li & 1;
    const int jo = i & 1;             // component written this layer
    const bool upd0 = (jo == 0);      // jo==0: input comp is z1, output z0

    // high-reuse per-layer constants into registers (used 8x per layer each)
    uint4 af[2][8];
    #pragma unroll
    for (int m = 0; m < 2; ++m)
      #pragma unroll
      for (int f = 0; f < 8; ++f)
        af[m][f] = sm.afr[cur][m][f][lane];

    float c1v[2][16], b1r[2][16];
    #pragma unroll
    for (int m = 0; m < 2; ++m)
      #pragma unroll
      for (int q = 0; q < 2; ++q)
        #pragma unroll
        for (int e2 = 0; e2 < 4; ++e2) {
          float4 v = *(const float4*)&sm.c1b1[i][m][q * 32 + 8 * g + e2 * 2];
          c1v[m][q * 8 + e2 * 2]     = v.x; b1r[m][q * 8 + e2 * 2]     = v.y;
          c1v[m][q * 8 + e2 * 2 + 1] = v.z; b1r[m][q * 8 + e2 * 2 + 1] = v.w;
        }
    const float b3s = sB3[i * 2 + jo];
    const float b3t = tB3[i * 2 + jo];

    if (li < 5) stage_layer(&sm, sW2, tW2, i - 1, cur ^ 1, tid);  // prefetch next layer

    #pragma unroll 1
    for (int t = 0; t < T_TILES; ++t) {
      const int widx = wbase + t * 16 + pr;
      float4 zv = sm.zst[widx];                 // (z0, z1, ldet, -)
      const float zin = upd0 ? zv.y : zv.x;     // masked-in component z[jm]
      float pre[2];
      #pragma unroll
      for (int m = 0; m < 2; ++m) {
        // w3/b2 pack for this lane-group: JIT read (broadcast within group)
        unsigned wv[16];
        #pragma unroll
        for (int n = 0; n < 4; ++n) {
          uint4 v = *(const uint4*)&sm.wb[i][m][n * 16 + 4 * g];
          wv[n * 4 + 0] = v.x; wv[n * 4 + 1] = v.y;
          wv[n * 4 + 2] = v.z; wv[n * 4 + 3] = v.w;
        }
        f4_t acc[4];
        #pragma unroll
        for (int n = 0; n < 4; ++n)
          #pragma unroll
          for (int r = 0; r < 4; ++r)
            acc[n][r] = __uint_as_float(wv[n * 4 + r] << 16);   // init with b2
        #pragma unroll
        for (int q = 0; q < 2; ++q) {
          // layer 1: h1 = leaky(w1[:,jm]*zin + b1), this lane's 8 k-slots, as bf16 B-frag
          unsigned bb[4];
          #pragma unroll
          for (int e2 = 0; e2 < 4; ++e2) {
            float h0 = fmaf(c1v[m][q * 8 + e2 * 2],     zin, b1r[m][q * 8 + e2 * 2]);
            float h1 = fmaf(c1v[m][q * 8 + e2 * 2 + 1], zin, b1r[m][q * 8 + e2 * 2 + 1]);
            h0 = fmaxf(h0, 0.01f * h0);
            h1 = fmaxf(h1, 0.01f * h1);
            bb[e2] = pkbf(h0, h1);
          }
          bfrag_t B = __builtin_bit_cast(bfrag_t, make_uint4(bb[0], bb[1], bb[2], bb[3]));
          #pragma unroll
          for (int n = 0; n < 4; ++n)
            acc[n] = __builtin_amdgcn_mfma_f32_16x16x32_bf16(
                __builtin_bit_cast(bfrag_t, af[m][q * 4 + n]), B, acc[n], 0, 0, 0);
        }
        // layer 3: leaky(h2), dot with w3[jo], reduce over the 4 lane-groups
        float part = 0.f;
        #pragma unroll
        for (int n = 0; n < 4; ++n)
          #pragma unroll
          for (int r = 0; r < 4; ++r) {
            float h2 = acc[n][r];
            h2 = fmaxf(h2, 0.01f * h2);
            part = fmaf(__uint_as_float(wv[n * 4 + r] & 0xffff0000u), h2, part);
          }
        part += __shfl_xor(part, 16);
        part += __shfl_xor(part, 32);
        pre[m] = part;
      }
      // coupling update (identical across the 4 lane-groups)
      float esv = __expf(2.f * (pre[0] + b3s));
      float sv  = 1.f - 2.f / (esv + 1.f);          // tanh
      float tv  = pre[1] + b3t;
      float zo  = upd0 ? zv.x : zv.y;
      float zn  = (zo - tv) * __expf(-sv);
      if (upd0) zv.x = zn; else zv.y = zn;
      zv.z -= sv;
      if (g == 0) sm.zst[widx] = zv;
    }
    __syncthreads();
  }

  // ---- epilogue: prior + logdet -> loss contribution; reduce ----
  float csum = 0.f;
  #pragma unroll 1
  for (int t = 0; t < T_TILES; ++t) {
    const int widx = wbase + t * 16 + pr;
    float4 zv = sm.zst[widx];
    float2 bw = sm.btw[widx];
    float prior = -0.5f * (zv.x * zv.x + zv.y * zv.y) - LOG_2PI;
    float lphi  = prior + zv.z;
    csum += (bw.x - 2.f * lphi) * bw.y;
  }
  #pragma unroll
  for (int off = 1; off <= 32; off <<= 1)
    csum += __shfl_xor(csum, off);
  if (lane == 0) sm.wsum[wave] = csum;
  __syncthreads();
  if (tid == 0) {
    float tot = sm.wsum[0] + sm.wsum[1] + sm.wsum[2] + sm.wsum[3];
    // /4 for the 4x group replication, /8192 = /pred.shape[0]
    atomicAdd(out, tot * (1.0f / 32768.0f));
  }
}

extern "C" void kernel_launch(void* const* d_in, const int* in_sizes, int n_in,
                              void* d_out, int out_size, void* d_ws, size_t ws_size,
                              hipStream_t stream) {
  const float* pred = (const float*)d_in[0];
  const float* targ = (const float*)d_in[1];
  const float* twp  = (const float*)d_in[2];
  const float* sW1 = (const float*)d_in[3];  const float* sB1 = (const float*)d_in[4];
  const float* sW2 = (const float*)d_in[5];  const float* sB2 = (const float*)d_in[6];
  const float* sW3 = (const float*)d_in[7];  const float* sB3 = (const float*)d_in[8];
  const float* tW1 = (const float*)d_in[9];  const float* tB1 = (const float*)d_in[10];
  const float* tW2 = (const float*)d_in[11]; const float* tB2 = (const float*)d_in[12];
  const float* tW3 = (const float*)d_in[13]; const float* tB3 = (const float*)d_in[14];

  const int M = in_sizes[2];               // N*K points
  const int blocks = (M + PTS_BLK - 1) / PTS_BLK;

  hipMemsetAsync(d_out, 0, sizeof(float), stream);
  hipLaunchKernelGGL(ihll_kernel, dim3(blocks), dim3(BLOCK), 0, stream,
                     pred, targ, twp, sW1, sB1, sW2, sB2, sW3, sB3,
                     tW1, tB1, tW2, tB2, tW3, tB3, (float*)d_out, M);
}